// Round 6
// baseline (192.148 us; speedup 1.0000x reference)
//
#include <hip/hip_runtime.h>
#include <math.h>

// x,y: [B, C] fp32; u: scalar fp32.
#define B_ROWS 65536
#define C_COLS 1024
#define NBLOCKS 2048
#define WPB 4
#define NWAVES (NBLOCKS * WPB)   // 8192 waves
#define RPW (B_ROWS / NWAVES)    // 8 rows per wave

typedef float v4f __attribute__((ext_vector_type(4)));

// Round-3 winner structure (94.3us), VERBATIM stage 1. Critical:
// __launch_bounds__(256) — without it hipcc assumes 1024-thread blocks and
// caps VGPRs at 64, which can't hold the 64-reg double buffer; loads then
// serialize (round 5: 60 VGPR -> 1.43 TB/s; round 4: 32 VGPR -> 2.47 TB/s;
// uncapped ~128 VGPR -> 5.7+ TB/s). Occupancy 4 waves/SIMD is ENOUGH when
// each wave keeps 16 v4f loads in flight — do not trade MLP for waves.
// Stage 2 fused via last-block ticket (saves the ~5us 1-block dispatch).
__global__ __launch_bounds__(256) void mnl_fused_kernel(
    const float* __restrict__ x,
    const float* __restrict__ y,
    const float* __restrict__ u,
    float* __restrict__ partial,
    unsigned* __restrict__ cnt,     // zeroed by memset node each call
    float* __restrict__ out) {
  const int wave = threadIdx.x >> 6;
  const int lane = threadIdx.x & 63;
  const int gwave = blockIdx.x * WPB + wave;
  const long long row0 = (long long)gwave * RPW;
  const float u0 = u[0];

  const v4f* __restrict__ xb = (const v4f*)x;
  const v4f* __restrict__ yb = (const v4f*)y;

  float se[RPW], sxy[RPW];
  unsigned choice = 0;

  v4f cx[4], cy[4], nx[4], ny[4];

  // prologue: row 0 (nontemporal: streamed once)
  {
    const v4f* xr = xb + row0 * (C_COLS / 4) + lane;
    const v4f* yr = yb + row0 * (C_COLS / 4) + lane;
#pragma unroll
    for (int i = 0; i < 4; ++i) {
      cx[i] = __builtin_nontemporal_load(xr + 64 * i);
      cy[i] = __builtin_nontemporal_load(yr + 64 * i);
    }
  }

#pragma unroll
  for (int r = 0; r < RPW; ++r) {
    if (r + 1 < RPW) {   // prefetch next row while summing current
      const v4f* xr = xb + (row0 + r + 1) * (C_COLS / 4) + lane;
      const v4f* yr = yb + (row0 + r + 1) * (C_COLS / 4) + lane;
#pragma unroll
      for (int i = 0; i < 4; ++i) {
        nx[i] = __builtin_nontemporal_load(xr + 64 * i);
        ny[i] = __builtin_nontemporal_load(yr + 64 * i);
      }
    }

    float se_l = 0.f, sxy_l = 0.f, sy_l = 0.f;
#pragma unroll
    for (int i = 0; i < 4; ++i) {
      se_l  += __expf(cx[i].x) + __expf(cx[i].y) +
               __expf(cx[i].z) + __expf(cx[i].w);
      sxy_l += cx[i].x * cy[i].x + cx[i].y * cy[i].y +
               cx[i].z * cy[i].z + cx[i].w * cy[i].w;
      sy_l  += cy[i].x + cy[i].y + cy[i].z + cy[i].w;
    }
    se[r] = se_l;
    sxy[r] = sxy_l;
    choice |= (__any(sy_l > 0.f) ? 1u : 0u) << r;   // one ballot per row

#pragma unroll
    for (int i = 0; i < 4; ++i) { cx[i] = nx[i]; cy[i] = ny[i]; }
  }

  // Batched butterflies: 8 rows x 2 vars = 16 independent DS ops per step.
#pragma unroll
  for (int off = 1; off < 64; off <<= 1) {
#pragma unroll
    for (int r = 0; r < RPW; ++r) {
      se[r]  += __shfl_xor(se[r],  off, 64);
      sxy[r] += __shfl_xor(sxy[r], off, 64);
    }
  }

  // 8 independent transcendental tails; result uniform across lanes.
  float acc = 0.f;
#pragma unroll
  for (int r = 0; r < RPW; ++r) {
    const float lse = __logf(se[r]);                             // logsumexp
    const float a = fmaxf(u0, lse);
    const float logden = a + log1pf(__expf(-fabsf(u0 - lse)));   // logaddexp
    const float s = ((choice >> r) & 1u) ? sxy[r] : u0;
    acc += s - logden;
  }

  __shared__ float sh[WPB];
  __shared__ bool is_last;
  if (lane == 0) sh[wave] = acc;
  __syncthreads();
  if (threadIdx.x == 0) {
    partial[blockIdx.x] = sh[0] + sh[1] + sh[2] + sh[3];
    __threadfence();                          // release partial before ticket
    const unsigned old = atomicAdd(cnt, 1u);  // device-scope by default
    is_last = (old == NBLOCKS - 1);
  }
  __syncthreads();

  if (is_last) {
    __threadfence();                          // acquire all partials
    const volatile float* vp = partial;       // bypass stale L1
    float a2 = 0.f;
    for (int i = threadIdx.x; i < NBLOCKS; i += 256) a2 += vp[i];
#pragma unroll
    for (int off = 1; off < 64; off <<= 1) a2 += __shfl_xor(a2, off, 64);

    __shared__ float sh2[WPB];
    if (lane == 0) sh2[wave] = a2;
    __syncthreads();
    if (threadIdx.x == 0) {
      const float t = sh2[0] + sh2[1] + sh2[2] + sh2[3];
      const float scale = 1.0f / (2.302585092994046f * (float)B_ROWS);
      out[0] = -t * scale;   // -mean( (s - logden)/ln10 )
    }
  }
}

extern "C" void kernel_launch(void* const* d_in, const int* in_sizes, int n_in,
                              void* d_out, int out_size, void* d_ws, size_t ws_size,
                              hipStream_t stream) {
  const float* x = (const float*)d_in[0];
  const float* y = (const float*)d_in[1];
  const float* u = (const float*)d_in[2];
  float* out = (float*)d_out;
  float* partial = (float*)d_ws;                       // 2048 floats = 8 KiB
  unsigned* cnt = (unsigned*)((char*)d_ws + NBLOCKS * sizeof(float));

  // Counter must start at 0 every call (ws is poisoned to 0xAA once and
  // never re-poisoned). 4-byte memset node: ~1us, graph-capturable.
  hipMemsetAsync(cnt, 0, sizeof(unsigned), stream);

  mnl_fused_kernel<<<NBLOCKS, 256, 0, stream>>>(x, y, u, partial, cnt, out);
}

// Round 7
// 189.034 us; speedup vs baseline: 1.0165x; 1.0165x over previous
//
#include <hip/hip_runtime.h>
#include <math.h>

// x,y: [B, C] fp32; u: scalar fp32.
#define B_ROWS 65536
#define C_COLS 1024
#define NBLOCKS 2048
#define WPB 4
#define NWAVES (NBLOCKS * WPB)   // 8192 waves
#define RPW (B_ROWS / NWAVES)    // 8 rows per wave

typedef float v4f __attribute__((ext_vector_type(4)));

// Round-3 winner structure + fused last-block-ticket reduction.
//
// REGISTER-ALLOCATION PIN (the whole game on this kernel):
//   VGPR history: 32 -> 2.5 TB/s, 60 -> 1.43, 80 -> 1.41, ~128 -> ~6 TB/s.
//   The 2-row double buffer is 64 VGPRs of row data; if the backend targets
//   >4 waves/EU it "saves" registers by serializing the prefetch loads,
//   collapsing memory-level parallelism. __launch_bounds__ is only a CAP;
//   amdgpu_waves_per_eu(4,4) pins the occupancy TARGET at 4 waves/EU
//   (VGPR budget 512/4=128), removing the incentive to serialize.
__global__ __launch_bounds__(256)
__attribute__((amdgpu_waves_per_eu(4, 4)))
void mnl_fused_kernel(
    const float* __restrict__ x,
    const float* __restrict__ y,
    const float* __restrict__ u,
    float* __restrict__ partial,
    unsigned* __restrict__ cnt,     // zeroed by memset node each call
    float* __restrict__ out) {
  const int wave = threadIdx.x >> 6;
  const int lane = threadIdx.x & 63;
  const int gwave = blockIdx.x * WPB + wave;
  const long long row0 = (long long)gwave * RPW;
  const float u0 = u[0];

  const v4f* __restrict__ xb = (const v4f*)x;
  const v4f* __restrict__ yb = (const v4f*)y;

  float se[RPW], sxy[RPW];
  unsigned choice = 0;

  v4f cx[4], cy[4], nx[4], ny[4];

  // prologue: row 0 (nontemporal: streamed once)
  {
    const v4f* xr = xb + row0 * (C_COLS / 4) + lane;
    const v4f* yr = yb + row0 * (C_COLS / 4) + lane;
#pragma unroll
    for (int i = 0; i < 4; ++i) {
      cx[i] = __builtin_nontemporal_load(xr + 64 * i);
      cy[i] = __builtin_nontemporal_load(yr + 64 * i);
    }
  }

#pragma unroll
  for (int r = 0; r < RPW; ++r) {
    if (r + 1 < RPW) {   // prefetch next row while summing current
      const v4f* xr = xb + (row0 + r + 1) * (C_COLS / 4) + lane;
      const v4f* yr = yb + (row0 + r + 1) * (C_COLS / 4) + lane;
#pragma unroll
      for (int i = 0; i < 4; ++i) {
        nx[i] = __builtin_nontemporal_load(xr + 64 * i);
        ny[i] = __builtin_nontemporal_load(yr + 64 * i);
      }
    }

    float se_l = 0.f, sxy_l = 0.f, sy_l = 0.f;
#pragma unroll
    for (int i = 0; i < 4; ++i) {
      se_l  += __expf(cx[i].x) + __expf(cx[i].y) +
               __expf(cx[i].z) + __expf(cx[i].w);
      sxy_l += cx[i].x * cy[i].x + cx[i].y * cy[i].y +
               cx[i].z * cy[i].z + cx[i].w * cy[i].w;
      sy_l  += cy[i].x + cy[i].y + cy[i].z + cy[i].w;
    }
    se[r] = se_l;
    sxy[r] = sxy_l;
    choice |= (__any(sy_l > 0.f) ? 1u : 0u) << r;   // one ballot per row

#pragma unroll
    for (int i = 0; i < 4; ++i) { cx[i] = nx[i]; cy[i] = ny[i]; }
  }

  // Batched butterflies: 8 rows x 2 vars = 16 independent DS ops per step.
#pragma unroll
  for (int off = 1; off < 64; off <<= 1) {
#pragma unroll
    for (int r = 0; r < RPW; ++r) {
      se[r]  += __shfl_xor(se[r],  off, 64);
      sxy[r] += __shfl_xor(sxy[r], off, 64);
    }
  }

  // 8 independent transcendental tails; result uniform across lanes.
  float acc = 0.f;
#pragma unroll
  for (int r = 0; r < RPW; ++r) {
    const float lse = __logf(se[r]);                             // logsumexp
    const float a = fmaxf(u0, lse);
    const float logden = a + log1pf(__expf(-fabsf(u0 - lse)));   // logaddexp
    const float s = ((choice >> r) & 1u) ? sxy[r] : u0;
    acc += s - logden;
  }

  __shared__ float sh[WPB];
  __shared__ bool is_last;
  if (lane == 0) sh[wave] = acc;
  __syncthreads();
  if (threadIdx.x == 0) {
    partial[blockIdx.x] = sh[0] + sh[1] + sh[2] + sh[3];
    __threadfence();                          // release partial before ticket
    const unsigned old = atomicAdd(cnt, 1u);  // device-scope by default
    is_last = (old == NBLOCKS - 1);
  }
  __syncthreads();

  if (is_last) {
    __threadfence();                          // acquire all partials
    const volatile float* vp = partial;       // bypass stale L1
    float a2 = 0.f;
    for (int i = threadIdx.x; i < NBLOCKS; i += 256) a2 += vp[i];
#pragma unroll
    for (int off = 1; off < 64; off <<= 1) a2 += __shfl_xor(a2, off, 64);

    __shared__ float sh2[WPB];
    if (lane == 0) sh2[wave] = a2;
    __syncthreads();
    if (threadIdx.x == 0) {
      const float t = sh2[0] + sh2[1] + sh2[2] + sh2[3];
      const float scale = 1.0f / (2.302585092994046f * (float)B_ROWS);
      out[0] = -t * scale;   // -mean( (s - logden)/ln10 )
    }
  }
}

extern "C" void kernel_launch(void* const* d_in, const int* in_sizes, int n_in,
                              void* d_out, int out_size, void* d_ws, size_t ws_size,
                              hipStream_t stream) {
  const float* x = (const float*)d_in[0];
  const float* y = (const float*)d_in[1];
  const float* u = (const float*)d_in[2];
  float* out = (float*)d_out;
  float* partial = (float*)d_ws;                       // 2048 floats = 8 KiB
  unsigned* cnt = (unsigned*)((char*)d_ws + NBLOCKS * sizeof(float));

  // Counter must start at 0 every call (ws is poisoned to 0xAA once and
  // never re-poisoned). 4-byte memset node: ~1us, graph-capturable.
  hipMemsetAsync(cnt, 0, sizeof(unsigned), stream);

  mnl_fused_kernel<<<NBLOCKS, 256, 0, stream>>>(x, y, u, partial, cnt, out);
}